// Round 8
// baseline (68.474 us; speedup 1.0000x reference)
//
#include <hip/hip_runtime.h>

// QuadraticTimeVaryingVF via MFMA, single fused kernel (R8).
// out[n,h] = b[h] + sum_i o_i*(wlin[h,i] + sum_{j>=i} wq[h,i,j]*o_j)
// Per h: U[n,i] = wlin[i] + sum_{k<64} Wq[i,k]*o[n,k]   (wlin seeds the MFMA
// accumulator; C/D col=i is row-invariant). out = sum_i o_i*U_i + b, reduced
// from C-frags via shfl_xor.
//
// R7 post-mortem: kernel is ~4-6us; wall ~68 is dominated by harness floor
// (268MB d_ws poison-fill ~43us + restores ~6us + ~23 dispatch nodes/iter of
// graph gaps). R8 amortizes the last real redundancy: 1024-thread blocks
// process 4 n-tiles each (grid 256 = 1 block/CU, 32/XCD even), so weight
// stage+scatter runs 256x instead of 1024x. Same 4096 waves = 4/SIMD.

#define DOBS  64
#define NH    64
#define WROW  2145
#define NQUAD 2080            // upper-tri count
#define LSTR  72              // LDS row stride (bf16): 144 B, 16B-aligned
#define TILES 4

typedef unsigned short u16;
typedef __attribute__((ext_vector_type(8))) short short8;
typedef __attribute__((ext_vector_type(4))) short short4v;
typedef __attribute__((ext_vector_type(4))) float floatx4;

__device__ __forceinline__ u16 f2bf(float f) {   // RTNE, finite inputs
    unsigned u = __float_as_uint(f);
    return (u16)((u + 0x7FFF + ((u >> 16) & 1)) >> 16);
}
__device__ __forceinline__ float bf2f(u16 b) {
    return __uint_as_float(((unsigned)b) << 16);
}
__device__ __forceinline__ int tri_start(int i) {  // quad offset of row i
    return (i * (129 - i)) >> 1;                   // i*64 - i*(i-1)/2
}

__device__ __forceinline__ void scatter_w(u16* W16, int q, float v) {
    // q -> (i,j): i = floor((129 - sqrt(129^2 - 8q))/2) with +/-1 fixup
    const int t = 16641 - 8 * q;
    int i = (int)((129.0f - __builtin_sqrtf((float)t)) * 0.5f);
    i = (i < 0) ? 0 : ((i > 63) ? 63 : i);
    if (q < tri_start(i)) --i;
    if (q >= tri_start(i + 1)) ++i;
    const int j = i + (q - tri_start(i));
    W16[i * LSTR + j] = f2bf(v);
}

__global__ __launch_bounds__(1024) void qvf_main(
    const float* __restrict__ obs, const float* __restrict__ weights,
    const float* __restrict__ biases, float* __restrict__ out, int N)
{
    __shared__ u16 O16[TILES][DOBS * LSTR];  // o tiles [tile][n_local][k]
    __shared__ u16 W16[DOBS * LSTR];         // Wq      [i][k]
    __shared__ float LW[DOBS];               // wlin fp32

    const int tid  = threadIdx.x;
    const int h    = blockIdx.x & (NH - 1);
    const int sup  = blockIdx.x >> 6;            // super-tile 0..3
    const int n0   = sup * (TILES * 64);
    const int lane = tid & 63;
    const int wv   = tid >> 6;                   // 0..15
    const int tile = wv >> 2;                    // which n-tile this wave computes
    const int strip= wv & 3;                     // 16-row strip within tile

    const float* __restrict__ wsrc = weights + h * WROW;

    // ---- coalesced quad-weight loads (2080 = 1024+1024+32) ----
    const float wq0 = wsrc[DOBS + tid];
    const float wq1 = wsrc[DOBS + 1024 + tid];
    const float wq2 = (tid < NQUAD - 2048) ? wsrc[DOBS + 2048 + tid] : 0.f;

    if (tid < DOBS) LW[tid] = wsrc[tid];

    // zero W16 (below-diagonal must be 0): 4608 shorts = 576 short8 slots
    if (tid < 576) *(short8*)&W16[tid * 8] = (short8)0;

    // ---- obs staging: 4 tiles, fp32 -> bf16, coalesced float4 ----
    {
        const float* __restrict__ osrc = obs + ((size_t)n0 * NH + h) * DOBS;
#pragma unroll
        for (int p = 0; p < TILES; ++p) {             // p == tile index
            const int r  = (tid >> 4) & 63;           // local path row
            const int c4 = tid & 15;                  // float4 within row
            const floatx4 v = *(const floatx4*)(
                osrc + (size_t)(p * 64 + r) * (NH * DOBS) + c4 * 4);
            short4v sv;
            sv[0] = (short)f2bf(v.x); sv[1] = (short)f2bf(v.y);
            sv[2] = (short)f2bf(v.z); sv[3] = (short)f2bf(v.w);
            *(short4v*)&O16[p][r * LSTR + c4 * 4] = sv;
        }
    }
    __syncthreads();   // zeros visible before scatter

    // ---- scatter quad weights into W16 ----
    scatter_w(W16, tid, wq0);
    scatter_w(W16, 1024 + tid, wq1);
    if (tid < NQUAD - 2048) scatter_w(W16, 2048 + tid, wq2);
    __syncthreads();

    // ---- MFMA: wave (tile,strip) -> C rows strip*16..+15 of its tile ----
    const int col = lane & 15;
    const int qq  = lane >> 4;
    floatx4 acc[4];
#pragma unroll
    for (int ct = 0; ct < 4; ++ct) {
        const float wl = LW[ct * 16 + col];
        acc[ct][0] = wl; acc[ct][1] = wl; acc[ct][2] = wl; acc[ct][3] = wl;
    }

    const u16* __restrict__ Ot = O16[tile];
    const int mrow = strip * 16 + col;
#pragma unroll
    for (int ks = 0; ks < 2; ++ks) {
        const short8 a = *(const short8*)&Ot[mrow * LSTR + ks * 32 + qq * 8];
#pragma unroll
        for (int ct = 0; ct < 4; ++ct) {
            const int i = ct * 16 + col;
            const short8 b = *(const short8*)&W16[i * LSTR + ks * 32 + qq * 8];
            acc[ct] = __builtin_amdgcn_mfma_f32_16x16x32_bf16(a, b, acc[ct], 0, 0, 0);
        }
    }

    // ---- epilogue: out[n] = sum_i o[n,i]*U[n,i] + bias ----
    // C/D layout: col = lane&15 (i), row = qq*4 + reg (n within 16-strip)
    float P[4] = {0.f, 0.f, 0.f, 0.f};
#pragma unroll
    for (int ct = 0; ct < 4; ++ct) {
#pragma unroll
        for (int r = 0; r < 4; ++r) {
            const int row = strip * 16 + qq * 4 + r;
            const u16 ov = Ot[row * LSTR + ct * 16 + col];
            P[r] = fmaf(acc[ct][r], bf2f(ov), P[r]);
        }
    }
#pragma unroll
    for (int msk = 1; msk < 16; msk <<= 1) {
#pragma unroll
        for (int r = 0; r < 4; ++r) P[r] += __shfl_xor(P[r], msk, 64);
    }
    if (col == 0) {
        const float b = biases[h];
#pragma unroll
        for (int r = 0; r < 4; ++r) {
            const int row = strip * 16 + qq * 4 + r;
            out[(size_t)(n0 + tile * 64 + row) * NH + h] = P[r] + b;
        }
    }
}

extern "C" void kernel_launch(void* const* d_in, const int* in_sizes, int n_in,
                              void* d_out, int out_size, void* d_ws, size_t ws_size,
                              hipStream_t stream) {
    const float* obs     = (const float*)d_in[0];
    const float* weights = (const float*)d_in[1];
    const float* biases  = (const float*)d_in[2];
    float* out           = (float*)d_out;

    const int N = in_sizes[0] / (NH * DOBS);             // 1024
    qvf_main<<<dim3((N / (64 * TILES)) * NH), dim3(1024), 0, stream>>>(
        obs, weights, biases, out, N);
}